// Round 1
// baseline (169.227 us; speedup 1.0000x reference)
//
#include <hip/hip_runtime.h>
#include <hip/hip_bf16.h>

#define BB 64
#define TT 1024
#define NN 512
#define TCH 8
#define KT 32

static constexpr float THR = 0.15f;

typedef __attribute__((ext_vector_type(8))) short bf16x8;
typedef __attribute__((ext_vector_type(4))) float f32x4;

// ---------------- kernel A: partial column sums (s1, s2) ----------------
__global__ __launch_bounds__(512) void colsum_partial(
    const float* __restrict__ x, float* __restrict__ s1p, float* __restrict__ s2p) {
    int b = blockIdx.x;
    int c = blockIdx.y;
    int n = threadIdx.x;                 // 0..511, coalesced over n
    const float* xb = x + (size_t)b * TT * NN;
    float s1 = 0.f, s2 = 0.f;
    int t0 = c * (TT / TCH);
    #pragma unroll 4
    for (int t = t0; t < t0 + TT / TCH; ++t) {
        float v = xb[(size_t)t * NN + n];
        s1 += v;
        s2 += v * v;
    }
    s1p[((size_t)b * TCH + c) * NN + n] = s1;
    s2p[((size_t)b * TCH + c) * NN + n] = s2;
}

// ---------------- kernel A2: reduce partials -> s1, d ----------------
__global__ __launch_bounds__(512) void colsum_reduce(
    const float* __restrict__ s1p, const float* __restrict__ s2p,
    float* __restrict__ s1, float* __restrict__ dv) {
    int b = blockIdx.x;
    int n = threadIdx.x;
    float a = 0.f, q = 0.f;
    #pragma unroll
    for (int c = 0; c < TCH; ++c) {
        a += s1p[((size_t)b * TCH + c) * NN + n];
        q += s2p[((size_t)b * TCH + c) * NN + n];
    }
    s1[(size_t)b * NN + n] = a;
    dv[(size_t)b * NN + n] = q - a * a * (1.0f / TT);   // = cov_ii (unnormalized)
}

// ---------------- kernel B: split-bf16 MFMA SYRK, double-buffered single-barrier ----------------
// 128x128 output tile per block; 10 upper tiles x 64 batches = 640 blocks, 256 threads.
// LDS: 2 buffers x 32 KiB (Ah 0, Al 8K, Bh 16K, Bl 24K per buffer).
// Per K-iter: ONE barrier. Loads for iter t+1 issued before the MFMA block (in flight
// across compute), conversion+ds_write into the other buffer after the MFMAs.
// Split is exact-truncation Dekker: h = top16(v) (RTZ, free), r = v - trunc(v) (exact fp32),
// l = top16(r) (RTZ). Error in corr ~4e-7 << borderline-flip budget.
// Staging: thread owns a col-PAIR x 16 t's -> dwordx2 loads (8B/lane, halves load count).
// ds_write parity swizzle: pc = cs ^ ((cp>>2)&1) keeps any 8 consecutive lanes on 8
// distinct 16B bank slots (conflict-free b128 writes, same property as previous layout).
__global__ __launch_bounds__(256, 2) void corr_mfma(
    const float* __restrict__ x, const float* __restrict__ s1,
    const float* __restrict__ dv, unsigned* __restrict__ fired) {
    __shared__ uint4 ldsbuf[4096];          // 64 KiB = 2 x 32 KiB
    char* base = (char*)ldsbuf;

    int id = blockIdx.x;
    // XCD-chunked swizzle (640 = 8 * 80): all 10 tiles of a batch land on one XCD
    int swz = ((id & 7) * 80) + (id >> 3);
    int b = swz / 10;
    int u = swz % 10;
    int ti = 0, rem = u;
    while (rem >= (4 - ti)) { rem -= (4 - ti); ++ti; }
    int tj = ti + rem;
    int i0 = ti * 128, j0 = tj * 128;
    bool diag = (ti == tj);

    const unsigned* xb = (const unsigned*)(x + (size_t)b * TT * NN);
    int tid = threadIdx.x;
    int wave = tid >> 6;
    int lane = tid & 63;
    int rl = lane & 15, kg = lane >> 4;

    // ---- staging role: panel sp, t-half th, col-pair cp ----
    int sp = tid >> 7;                      // 0 = i-panel (A), 1 = j-panel (B)
    int th = (tid >> 6) & 1;                // which 16 t's of the 32-K step
    int cp = tid & 63;                      // col pair 0..63 -> cols 2cp, 2cp+1
    int gcol = (sp ? j0 : i0) + 2 * cp;
    unsigned sg = (unsigned)(cp & 3);       // = ((col>>1)&3) for both cols of the pair
    unsigned sregion = sp ? 16384u : 0u;
    bool do_stage = !(diag && sp);          // diagonal tiles: stage A only

    auto do_loads = [&](int t0, uint2* v) {
        const unsigned* src = xb + (size_t)(t0 + th * 16) * NN + gcol;
        #pragma unroll
        for (int k = 0; k < 16; ++k)
            v[k] = *(const uint2*)(src + (size_t)k * NN);
    };
    auto do_write = [&](char* bufb, const uint2* v) {
        char* sh = bufb + sregion;
        char* sl = sh + 8192;
        #pragma unroll
        for (int cs = 0; cs < 2; ++cs) {
            int pc = cs ^ ((cp >> 2) & 1);          // lane-parity bank spread
            unsigned coll = (unsigned)(2 * cp + pc);
            #pragma unroll
            for (int g = 0; g < 2; ++g) {
                unsigned kgv = (unsigned)(th * 2 + g);
                unsigned h32[4], l32[4];
                #pragma unroll
                for (int p = 0; p < 4; ++p) {
                    unsigned u0 = pc ? v[g * 8 + 2 * p].y     : v[g * 8 + 2 * p].x;
                    unsigned u1 = pc ? v[g * 8 + 2 * p + 1].y : v[g * 8 + 2 * p + 1].x;
                    unsigned m0 = u0 & 0xFFFF0000u, m1 = u1 & 0xFFFF0000u;
                    float r0 = __uint_as_float(u0) - __uint_as_float(m0);  // exact
                    float r1 = __uint_as_float(u1) - __uint_as_float(m1);  // exact
                    h32[p] = (u0 >> 16) | m1;
                    l32[p] = (__float_as_uint(r0) >> 16) | (__float_as_uint(r1) & 0xFFFF0000u);
                }
                unsigned off = coll * 64u + (((kgv ^ sg) & 3u) << 4);
                *(uint4*)(sh + off) = make_uint4(h32[0], h32[1], h32[2], h32[3]);
                *(uint4*)(sl + off) = make_uint4(l32[0], l32[1], l32[2], l32[3]);
            }
        }
    };

    // ---- compute role ----
    int wr = wave >> 1, wc = wave & 1;
    f32x4 acc[4][4];
    #pragma unroll
    for (int i = 0; i < 4; ++i)
        #pragma unroll
        for (int j = 0; j < 4; ++j)
            acc[i][j] = (f32x4)0.0f;

    unsigned aoff[4], boff[4];
    #pragma unroll
    for (int f = 0; f < 4; ++f) {
        unsigned ca = (unsigned)(64 * wr + 16 * f + rl);
        aoff[f] = ca * 64u + ((((unsigned)kg ^ ((ca >> 1) & 3u)) & 3u) << 4);
        unsigned cb = (unsigned)(64 * wc + 16 * f + rl);
        boff[f] = cb * 64u + ((((unsigned)kg ^ ((cb >> 1) & 3u)) & 3u) << 4);
    }

    // prologue: stage iter 0 into buffer 0
    {
        uint2 v[16];
        if (do_stage) {
            do_loads(0, v);
            do_write(base, v);
        }
    }

    int cur = 0;
    for (int it = 0; it < 32; ++it) {
        __syncthreads();                     // buf[cur] ready; buf[cur^1] reads long done

        uint2 v[16];
        bool more = (it < 31);
        if (do_stage && more)
            do_loads((it + 1) * KT, v);      // in flight across the MFMA block

        const char* cb = base + (cur << 15);
        const char* arh = cb;
        const char* arl = cb + 8192;
        const char* brh = cb + (diag ? 0 : 16384);
        const char* brl = cb + (diag ? 8192 : 24576);

        bf16x8 Ah[4], Al[4];
        #pragma unroll
        for (int f = 0; f < 4; ++f) {
            Ah[f] = *(const bf16x8*)(arh + aoff[f]);
            Al[f] = *(const bf16x8*)(arl + aoff[f]);
        }
        #pragma unroll
        for (int fj = 0; fj < 4; ++fj) {
            bf16x8 Bh = *(const bf16x8*)(brh + boff[fj]);
            bf16x8 Bl = *(const bf16x8*)(brl + boff[fj]);
            #pragma unroll
            for (int fi = 0; fi < 4; ++fi) {
                acc[fi][fj] = __builtin_amdgcn_mfma_f32_16x16x32_bf16(Ah[fi], Bh, acc[fi][fj], 0, 0, 0);
                acc[fi][fj] = __builtin_amdgcn_mfma_f32_16x16x32_bf16(Ah[fi], Bl, acc[fi][fj], 0, 0, 0);
                acc[fi][fj] = __builtin_amdgcn_mfma_f32_16x16x32_bf16(Al[fi], Bh, acc[fi][fj], 0, 0, 0);
            }
        }

        if (do_stage && more)
            do_write(base + ((cur ^ 1) << 15), v);   // vmcnt wait lands after MFMA issue
        cur ^= 1;
    }

    // ---- epilogue: cov = acc - s1_i*s1_j/T; fired if cov^2 > thr^2*d_i*d_j, j>i ----
    const float thr2 = THR * THR;
    const float invT = 1.0f / TT;
    const float* s1b = s1 + (size_t)b * NN;
    const float* dvb = dv + (size_t)b * NN;
    unsigned* fb = fired + (size_t)b * NN;
    int rowb = i0 + 64 * wr + (lane >> 4) * 4;
    int colb = j0 + 64 * wc + rl;
    #pragma unroll
    for (int fj = 0; fj < 4; ++fj) {
        int gj = colb + 16 * fj;
        float sj = s1b[gj], dj = dvb[gj];
        #pragma unroll
        for (int fi = 0; fi < 4; ++fi) {
            int gi0 = rowb + 16 * fi;
            #pragma unroll
            for (int r = 0; r < 4; ++r) {
                int gi = gi0 + r;
                if (gj > gi) {
                    float cov = acc[fi][fj][r] - s1b[gi] * sj * invT;
                    float lim = thr2 * dvb[gi] * dj;
                    if (cov * cov > lim) atomicOr(&fb[gi], 1u);
                }
            }
        }
    }
}

// ---------------- kernel C: finalize mask ----------------
__global__ __launch_bounds__(512) void finalize_mask(
    const unsigned* __restrict__ fired, float* __restrict__ out) {
    int b = blockIdx.x;
    int n = threadIdx.x;                  // 512
    unsigned f = fired[(size_t)b * NN + n];
    __shared__ int wsum[8];
    unsigned long long m = __ballot(f != 0u);
    int lane = n & 63;
    int w = n >> 6;
    if (lane == 0) wsum[w] = __popcll(m);
    __syncthreads();
    int cnt = 0;
    #pragma unroll
    for (int i = 0; i < 8; ++i) cnt += wsum[i];
    float val = (cnt == 0) ? 1.0f : ((cnt == 1) ? (f ? 1.0f : 0.0f) : 0.0f);
    out[(size_t)b * NN + n] = val;
}

extern "C" void kernel_launch(void* const* d_in, const int* in_sizes, int n_in,
                              void* d_out, int out_size, void* d_ws, size_t ws_size,
                              hipStream_t stream) {
    const float* x = (const float*)d_in[0];
    float* out = (float*)d_out;

    // ws layout
    float* s1p = (float*)d_ws;                       // B*TCH*N
    float* s2p = s1p + (size_t)BB * TCH * NN;        // B*TCH*N
    float* s1  = s2p + (size_t)BB * TCH * NN;        // B*N
    float* dv  = s1  + (size_t)BB * NN;              // B*N
    unsigned* fired = (unsigned*)(dv + (size_t)BB * NN); // B*N

    hipMemsetAsync(fired, 0, (size_t)BB * NN * sizeof(unsigned), stream);

    colsum_partial<<<dim3(BB, TCH), 512, 0, stream>>>(x, s1p, s2p);
    colsum_reduce<<<BB, 512, 0, stream>>>(s1p, s2p, s1, dv);
    corr_mfma<<<dim3(640), 256, 0, stream>>>(x, s1, dv, fired);
    finalize_mask<<<BB, 512, 0, stream>>>(fired, out);
}

// Round 2
// 130.229 us; speedup vs baseline: 1.2995x; 1.2995x over previous
//
#include <hip/hip_runtime.h>
#include <hip/hip_bf16.h>

#define BB 64
#define TT 1024
#define NN 512
#define TCH 8
#define KT 32

static constexpr float THR = 0.15f;

typedef __attribute__((ext_vector_type(8))) short bf16x8;
typedef __attribute__((ext_vector_type(4))) float f32x4;

// ---------------- kernel A: partial column sums (s1, s2) ----------------
__global__ __launch_bounds__(512) void colsum_partial(
    const float* __restrict__ x, float* __restrict__ s1p, float* __restrict__ s2p) {
    int b = blockIdx.x;
    int c = blockIdx.y;
    int n = threadIdx.x;                 // 0..511, coalesced over n
    const float* xb = x + (size_t)b * TT * NN;
    float s1 = 0.f, s2 = 0.f;
    int t0 = c * (TT / TCH);
    #pragma unroll 4
    for (int t = t0; t < t0 + TT / TCH; ++t) {
        float v = xb[(size_t)t * NN + n];
        s1 += v;
        s2 += v * v;
    }
    s1p[((size_t)b * TCH + c) * NN + n] = s1;
    s2p[((size_t)b * TCH + c) * NN + n] = s2;
}

// ---------------- kernel A2: reduce partials -> s1, d ----------------
__global__ __launch_bounds__(512) void colsum_reduce(
    const float* __restrict__ s1p, const float* __restrict__ s2p,
    float* __restrict__ s1, float* __restrict__ dv) {
    int b = blockIdx.x;
    int n = threadIdx.x;
    float a = 0.f, q = 0.f;
    #pragma unroll
    for (int c = 0; c < TCH; ++c) {
        a += s1p[((size_t)b * TCH + c) * NN + n];
        q += s2p[((size_t)b * TCH + c) * NN + n];
    }
    s1[(size_t)b * NN + n] = a;
    dv[(size_t)b * NN + n] = q - a * a * (1.0f / TT);   // = cov_ii (unnormalized)
}

// ---------------- kernel B: split-bf16 MFMA SYRK ----------------
// 128x128 output tile per block; 10 upper tiles x 64 batches = 640 blocks.
// NOW 512 threads = 8 waves, wave-tile 32x64 (wr 0..3, wc 0..1) -> 2x the resident
// waves of the 4-wave version at identical grid/LDS (latency-bound kernel; occupancy
// was the measured limiter: 22% -> target ~45%).
// Proven 2-barrier structure: stage -> sync -> compute -> sync. 32 KiB LDS single buf
// (Ah 0, Al 8K, Bh 16K, Bl 24K), col-major [col][k], 64B col stride, slot-swizzle
//   byte(col,k) = col*64 + (((k>>3) ^ ((col>>1)&3))&3)*16 + (k&7)*2
// Staging: thread owns col-pair (cp of 128: 0-63 A, 64-127 B) x 8 k's (kq = tid>>7):
// 8x dwordx2 loads, RTZ Dekker split (h = top16(v), r = v - trunc(v) exact, l = top16(r)),
// 4x ds_write_b128 with parity order p = ((cp>>2)&1)^w -> all 8 bank-quads per 8 lanes
// (verified conflict-free in prior rounds: SQ_LDS_BANK_CONFLICT = 0).
__global__ __launch_bounds__(512, 4) void corr_mfma(
    const float* __restrict__ x, const float* __restrict__ s1,
    const float* __restrict__ dv, unsigned* __restrict__ fired) {
    __shared__ uint4 ldsbuf[2048];          // 32 KiB
    char* base = (char*)ldsbuf;

    int id = blockIdx.x;
    // XCD-chunked swizzle (640 = 8 * 80): all 10 tiles of a batch land on one XCD
    int swz = ((id & 7) * 80) + (id >> 3);
    int b = swz / 10;
    int u = swz % 10;
    int ti = 0, rem = u;
    while (rem >= (4 - ti)) { rem -= (4 - ti); ++ti; }
    int tj = ti + rem;
    int i0 = ti * 128, j0 = tj * 128;
    bool diag = (ti == tj);

    const unsigned* xb = (const unsigned*)(x + (size_t)b * TT * NN);
    int tid = threadIdx.x;
    int wave = tid >> 6;
    int lane = tid & 63;
    int rl = lane & 15, kg = lane >> 4;

    // ---- staging role: col-pair cp (0-63 A-panel, 64-127 B-panel), k-octet kq ----
    int cp = tid & 127;
    int kq = tid >> 7;                      // 0..3 -> k in [8*kq, 8*kq+8)
    int spanel = cp >> 6;                   // 0 = A (i-panel), 1 = B (j-panel)
    int pl = cp & 63;                       // pair index within panel -> cols 2pl, 2pl+1
    int gcol = (spanel ? j0 : i0) + 2 * pl;
    char* sh = base + (spanel ? 16384 : 0);
    char* sl = sh + 8192;
    unsigned sg = (unsigned)(pl & 3);       // ((col>>1)&3) for both cols of the pair
    bool do_stage = !(diag && spanel);      // diagonal tiles: stage A only

    // ---- compute role: wave (wr, wc) owns rows [32*wr,+32) x cols [64*wc,+64) ----
    int wr = wave >> 1, wc = wave & 1;
    const char* arh = base;
    const char* arl = base + 8192;
    const char* brh = base + (diag ? 0 : 16384);
    const char* brl = base + (diag ? 8192 : 24576);

    f32x4 acc[2][4];
    #pragma unroll
    for (int i = 0; i < 2; ++i)
        #pragma unroll
        for (int j = 0; j < 4; ++j)
            acc[i][j] = (f32x4)0.0f;

    unsigned aoff[2], boff[4];
    #pragma unroll
    for (int f = 0; f < 2; ++f) {
        unsigned ca = (unsigned)(32 * wr + 16 * f + rl);
        aoff[f] = ca * 64u + ((((unsigned)kg ^ ((ca >> 1) & 3u)) & 3u) << 4);
    }
    #pragma unroll
    for (int f = 0; f < 4; ++f) {
        unsigned cb = (unsigned)(64 * wc + 16 * f + rl);
        boff[f] = cb * 64u + ((((unsigned)kg ^ ((cb >> 1) & 3u)) & 3u) << 4);
    }

    for (int t0 = 0; t0 < TT; t0 += KT) {
        if (do_stage) {
            uint2 v[8];
            const unsigned* src = xb + (size_t)(t0 + 8 * kq) * NN + gcol;
            #pragma unroll
            for (int j = 0; j < 8; ++j)
                v[j] = *(const uint2*)(src + (size_t)j * NN);
            #pragma unroll
            for (int w = 0; w < 2; ++w) {
                int p = (((cp >> 2) & 1) ^ w);      // bank-quad parity order
                unsigned coll = (unsigned)(2 * pl + p);
                unsigned h32[4], l32[4];
                #pragma unroll
                for (int q = 0; q < 4; ++q) {
                    unsigned u0 = p ? v[2 * q].y     : v[2 * q].x;
                    unsigned u1 = p ? v[2 * q + 1].y : v[2 * q + 1].x;
                    unsigned m0 = u0 & 0xFFFF0000u, m1 = u1 & 0xFFFF0000u;
                    float r0 = __uint_as_float(u0) - __uint_as_float(m0);  // exact
                    float r1 = __uint_as_float(u1) - __uint_as_float(m1);  // exact
                    h32[q] = (u0 >> 16) | m1;
                    l32[q] = (__float_as_uint(r0) >> 16) | (__float_as_uint(r1) & 0xFFFF0000u);
                }
                unsigned off = coll * 64u + ((((unsigned)kq ^ sg) & 3u) << 4);
                *(uint4*)(sh + off) = make_uint4(h32[0], h32[1], h32[2], h32[3]);
                *(uint4*)(sl + off) = make_uint4(l32[0], l32[1], l32[2], l32[3]);
            }
        }
        __syncthreads();

        bf16x8 Ah[2], Al[2];
        #pragma unroll
        for (int f = 0; f < 2; ++f) {
            Ah[f] = *(const bf16x8*)(arh + aoff[f]);
            Al[f] = *(const bf16x8*)(arl + aoff[f]);
        }
        #pragma unroll
        for (int fj = 0; fj < 4; ++fj) {
            bf16x8 Bh = *(const bf16x8*)(brh + boff[fj]);
            bf16x8 Bl = *(const bf16x8*)(brl + boff[fj]);
            #pragma unroll
            for (int fi = 0; fi < 2; ++fi) {
                acc[fi][fj] = __builtin_amdgcn_mfma_f32_16x16x32_bf16(Ah[fi], Bh, acc[fi][fj], 0, 0, 0);
                acc[fi][fj] = __builtin_amdgcn_mfma_f32_16x16x32_bf16(Ah[fi], Bl, acc[fi][fj], 0, 0, 0);
                acc[fi][fj] = __builtin_amdgcn_mfma_f32_16x16x32_bf16(Al[fi], Bh, acc[fi][fj], 0, 0, 0);
            }
        }
        __syncthreads();
    }

    // ---- epilogue: cov = acc - s1_i*s1_j/T; fired if cov^2 > thr^2*d_i*d_j, j>i ----
    const float thr2 = THR * THR;
    const float invT = 1.0f / TT;
    const float* s1b = s1 + (size_t)b * NN;
    const float* dvb = dv + (size_t)b * NN;
    unsigned* fb = fired + (size_t)b * NN;
    int rowb = i0 + 32 * wr + (lane >> 4) * 4;
    int colb = j0 + 64 * wc + rl;
    #pragma unroll
    for (int fj = 0; fj < 4; ++fj) {
        int gj = colb + 16 * fj;
        float sj = s1b[gj], dj = dvb[gj];
        #pragma unroll
        for (int fi = 0; fi < 2; ++fi) {
            int gi0 = rowb + 16 * fi;
            #pragma unroll
            for (int r = 0; r < 4; ++r) {
                int gi = gi0 + r;
                if (gj > gi) {
                    float cov = acc[fi][fj][r] - s1b[gi] * sj * invT;
                    float lim = thr2 * dvb[gi] * dj;
                    if (cov * cov > lim) atomicOr(&fb[gi], 1u);
                }
            }
        }
    }
}

// ---------------- kernel C: finalize mask ----------------
__global__ __launch_bounds__(512) void finalize_mask(
    const unsigned* __restrict__ fired, float* __restrict__ out) {
    int b = blockIdx.x;
    int n = threadIdx.x;                  // 512
    unsigned f = fired[(size_t)b * NN + n];
    __shared__ int wsum[8];
    unsigned long long m = __ballot(f != 0u);
    int lane = n & 63;
    int w = n >> 6;
    if (lane == 0) wsum[w] = __popcll(m);
    __syncthreads();
    int cnt = 0;
    #pragma unroll
    for (int i = 0; i < 8; ++i) cnt += wsum[i];
    float val = (cnt == 0) ? 1.0f : ((cnt == 1) ? (f ? 1.0f : 0.0f) : 0.0f);
    out[(size_t)b * NN + n] = val;
}

extern "C" void kernel_launch(void* const* d_in, const int* in_sizes, int n_in,
                              void* d_out, int out_size, void* d_ws, size_t ws_size,
                              hipStream_t stream) {
    const float* x = (const float*)d_in[0];
    float* out = (float*)d_out;

    // ws layout
    float* s1p = (float*)d_ws;                       // B*TCH*N
    float* s2p = s1p + (size_t)BB * TCH * NN;        // B*TCH*N
    float* s1  = s2p + (size_t)BB * TCH * NN;        // B*N
    float* dv  = s1  + (size_t)BB * NN;              // B*N
    unsigned* fired = (unsigned*)(dv + (size_t)BB * NN); // B*N

    hipMemsetAsync(fired, 0, (size_t)BB * NN * sizeof(unsigned), stream);

    colsum_partial<<<dim3(BB, TCH), 512, 0, stream>>>(x, s1p, s2p);
    colsum_reduce<<<BB, 512, 0, stream>>>(s1p, s2p, s1, dv);
    corr_mfma<<<dim3(640), 512, 0, stream>>>(x, s1, dv, fired);
    finalize_mask<<<BB, 512, 0, stream>>>(fired, out);
}

// Round 3
// 126.087 us; speedup vs baseline: 1.3422x; 1.0329x over previous
//
#include <hip/hip_runtime.h>
#include <hip/hip_bf16.h>

#define BB 64
#define TT 1024
#define NN 512
#define TCH 8
#define KT 32

static constexpr float THR = 0.15f;

typedef __attribute__((ext_vector_type(8))) short bf16x8;
typedef __attribute__((ext_vector_type(4))) float f32x4;

// ---------------- kernel A: partial column sums (s1, s2) ----------------
__global__ __launch_bounds__(512) void colsum_partial(
    const float* __restrict__ x, float* __restrict__ s1p, float* __restrict__ s2p) {
    int b = blockIdx.x;
    int c = blockIdx.y;
    int n = threadIdx.x;                 // 0..511, coalesced over n
    const float* xb = x + (size_t)b * TT * NN;
    float s1 = 0.f, s2 = 0.f;
    int t0 = c * (TT / TCH);
    #pragma unroll 4
    for (int t = t0; t < t0 + TT / TCH; ++t) {
        float v = xb[(size_t)t * NN + n];
        s1 += v;
        s2 += v * v;
    }
    s1p[((size_t)b * TCH + c) * NN + n] = s1;
    s2p[((size_t)b * TCH + c) * NN + n] = s2;
}

// ---------------- kernel A2: reduce partials -> s1, d ----------------
__global__ __launch_bounds__(512) void colsum_reduce(
    const float* __restrict__ s1p, const float* __restrict__ s2p,
    float* __restrict__ s1, float* __restrict__ dv) {
    int b = blockIdx.x;
    int n = threadIdx.x;
    float a = 0.f, q = 0.f;
    #pragma unroll
    for (int c = 0; c < TCH; ++c) {
        a += s1p[((size_t)b * TCH + c) * NN + n];
        q += s2p[((size_t)b * TCH + c) * NN + n];
    }
    s1[(size_t)b * NN + n] = a;
    dv[(size_t)b * NN + n] = q - a * a * (1.0f / TT);   // = cov_ii (unnormalized)
}

// ---------------- kernel B: split-bf16 MFMA SYRK ----------------
// 128x128 tile per block; 10 upper tiles x 64 batches = 640 blocks; 512 threads = 8
// waves, wave-tile 32x64. Proven round-2 structure (single 32 KiB buffer, 2 barriers
// per K-step, slot-swizzled col-major LDS, RTZ Dekker split) PLUS register prefetch:
// global loads for K-step t+1 are issued before barrier 1 of step t (double register
// set vA/vB, compile-time alternation), so their latency hides under the MFMA phase
// instead of being exposed at the top of the stage phase (the measured ~50% stall).
// LDS layout: Ah 0, Al 8K, Bh 16K, Bl 24K; byte(col,k) = col*64
//   + (((k>>3) ^ ((col>>1)&3))&3)*16 + (k&7)*2  -- verified conflict-free.
// Diagonal tiles: waves (wc==0, wr>=2) produce only below-diagonal output -> skip
// their ds_read+MFMA (barriers still executed by all waves).
__global__ __launch_bounds__(512, 4) void corr_mfma(
    const float* __restrict__ x, const float* __restrict__ s1,
    const float* __restrict__ dv, unsigned* __restrict__ fired) {
    __shared__ uint4 ldsbuf[2048];          // 32 KiB
    char* base = (char*)ldsbuf;

    int id = blockIdx.x;
    // XCD-chunked swizzle (640 = 8 * 80): all 10 tiles of a batch land on one XCD
    int swz = ((id & 7) * 80) + (id >> 3);
    int b = swz / 10;
    int u = swz % 10;
    int ti = 0, rem = u;
    while (rem >= (4 - ti)) { rem -= (4 - ti); ++ti; }
    int tj = ti + rem;
    int i0 = ti * 128, j0 = tj * 128;
    bool diag = (ti == tj);

    const unsigned* xb = (const unsigned*)(x + (size_t)b * TT * NN);
    int tid = threadIdx.x;
    int wave = tid >> 6;
    int lane = tid & 63;
    int rl = lane & 15, kg = lane >> 4;

    // ---- staging role: col-pair cp (0-63 A-panel, 64-127 B-panel), k-octet kq ----
    int cp = tid & 127;
    int kq = tid >> 7;                      // 0..3 -> k in [8*kq, 8*kq+8)
    int spanel = cp >> 6;                   // 0 = A (i-panel), 1 = B (j-panel)
    int pl = cp & 63;                       // pair index within panel -> cols 2pl, 2pl+1
    int gcol = (spanel ? j0 : i0) + 2 * pl;
    char* sh = base + (spanel ? 16384 : 0);
    char* sl = sh + 8192;
    unsigned sg = (unsigned)(pl & 3);       // ((col>>1)&3) for both cols of the pair
    bool do_stage = !(diag && spanel);      // diagonal tiles: stage A only

    auto LOADS = [&](uint2* v, int step) {
        const unsigned* src = xb + (size_t)(step * KT + 8 * kq) * NN + gcol;
        #pragma unroll
        for (int j = 0; j < 8; ++j)
            v[j] = *(const uint2*)(src + (size_t)j * NN);
    };
    auto WRITE = [&](const uint2* v) {
        #pragma unroll
        for (int w = 0; w < 2; ++w) {
            int p = (((cp >> 2) & 1) ^ w);      // bank-quad parity order
            unsigned coll = (unsigned)(2 * pl + p);
            unsigned h32[4], l32[4];
            #pragma unroll
            for (int q = 0; q < 4; ++q) {
                unsigned u0 = p ? v[2 * q].y     : v[2 * q].x;
                unsigned u1 = p ? v[2 * q + 1].y : v[2 * q + 1].x;
                unsigned m0 = u0 & 0xFFFF0000u, m1 = u1 & 0xFFFF0000u;
                float r0 = __uint_as_float(u0) - __uint_as_float(m0);  // exact
                float r1 = __uint_as_float(u1) - __uint_as_float(m1);  // exact
                h32[q] = (u0 >> 16) | m1;
                l32[q] = (__float_as_uint(r0) >> 16) | (__float_as_uint(r1) & 0xFFFF0000u);
            }
            unsigned off = coll * 64u + ((((unsigned)kq ^ sg) & 3u) << 4);
            *(uint4*)(sh + off) = make_uint4(h32[0], h32[1], h32[2], h32[3]);
            *(uint4*)(sl + off) = make_uint4(l32[0], l32[1], l32[2], l32[3]);
        }
    };

    // ---- compute role: wave (wr, wc) owns rows [32*wr,+32) x cols [64*wc,+64) ----
    int wr = wave >> 1, wc = wave & 1;
    const char* arh = base;
    const char* arl = base + 8192;
    const char* brh = base + (diag ? 0 : 16384);
    const char* brl = base + (diag ? 8192 : 24576);
    bool skip_mm = diag && (wc == 0) && (wr >= 2);   // fully below diagonal

    f32x4 acc[2][4];
    #pragma unroll
    for (int i = 0; i < 2; ++i)
        #pragma unroll
        for (int j = 0; j < 4; ++j)
            acc[i][j] = (f32x4)0.0f;

    unsigned aoff[2], boff[4];
    #pragma unroll
    for (int f = 0; f < 2; ++f) {
        unsigned ca = (unsigned)(32 * wr + 16 * f + rl);
        aoff[f] = ca * 64u + ((((unsigned)kg ^ ((ca >> 1) & 3u)) & 3u) << 4);
    }
    #pragma unroll
    for (int f = 0; f < 4; ++f) {
        unsigned cb = (unsigned)(64 * wc + 16 * f + rl);
        boff[f] = cb * 64u + ((((unsigned)kg ^ ((cb >> 1) & 3u)) & 3u) << 4);
    }

    #define COMPUTE()                                                                      \
        do {                                                                               \
            if (!skip_mm) {                                                                \
                bf16x8 Ah[2], Al[2];                                                       \
                _Pragma("unroll")                                                          \
                for (int f = 0; f < 2; ++f) {                                              \
                    Ah[f] = *(const bf16x8*)(arh + aoff[f]);                               \
                    Al[f] = *(const bf16x8*)(arl + aoff[f]);                               \
                }                                                                          \
                _Pragma("unroll")                                                          \
                for (int fj = 0; fj < 4; ++fj) {                                           \
                    bf16x8 Bh = *(const bf16x8*)(brh + boff[fj]);                          \
                    bf16x8 Bl = *(const bf16x8*)(brl + boff[fj]);                          \
                    _Pragma("unroll")                                                      \
                    for (int fi = 0; fi < 2; ++fi) {                                       \
                        acc[fi][fj] = __builtin_amdgcn_mfma_f32_16x16x32_bf16(             \
                            Ah[fi], Bh, acc[fi][fj], 0, 0, 0);                             \
                        acc[fi][fj] = __builtin_amdgcn_mfma_f32_16x16x32_bf16(             \
                            Ah[fi], Bl, acc[fi][fj], 0, 0, 0);                             \
                        acc[fi][fj] = __builtin_amdgcn_mfma_f32_16x16x32_bf16(             \
                            Al[fi], Bh, acc[fi][fj], 0, 0, 0);                             \
                    }                                                                      \
                }                                                                          \
            }                                                                              \
        } while (0)

    uint2 vA[8], vB[8];
    if (do_stage) LOADS(vA, 0);

    for (int it = 0; it < 32; it += 2) {
        // ---- step it: consume vA, prefetch vB (step it+1) ----
        if (do_stage) {
            LOADS(vB, it + 1);               // it+1 <= 31 always; in flight across compute
            WRITE(vA);                       // vmcnt wait for vA already satisfied
        }
        __syncthreads();
        COMPUTE();
        __syncthreads();
        // ---- step it+1: consume vB, prefetch vA (step it+2) ----
        if (do_stage) {
            if (it + 2 < 32) LOADS(vA, it + 2);
            WRITE(vB);
        }
        __syncthreads();
        COMPUTE();
        __syncthreads();
    }
    #undef COMPUTE

    // ---- epilogue: cov = acc - s1_i*s1_j/T; fired if cov^2 > thr^2*d_i*d_j, j>i ----
    const float thr2 = THR * THR;
    const float invT = 1.0f / TT;
    const float* s1b = s1 + (size_t)b * NN;
    const float* dvb = dv + (size_t)b * NN;
    unsigned* fb = fired + (size_t)b * NN;
    int rowb = i0 + 32 * wr + (lane >> 4) * 4;
    int colb = j0 + 64 * wc + rl;
    #pragma unroll
    for (int fj = 0; fj < 4; ++fj) {
        int gj = colb + 16 * fj;
        float sj = s1b[gj], dj = dvb[gj];
        #pragma unroll
        for (int fi = 0; fi < 2; ++fi) {
            int gi0 = rowb + 16 * fi;
            #pragma unroll
            for (int r = 0; r < 4; ++r) {
                int gi = gi0 + r;
                if (gj > gi) {
                    float cov = acc[fi][fj][r] - s1b[gi] * sj * invT;
                    float lim = thr2 * dvb[gi] * dj;
                    if (cov * cov > lim) atomicOr(&fb[gi], 1u);
                }
            }
        }
    }
}

// ---------------- kernel C: finalize mask ----------------
__global__ __launch_bounds__(512) void finalize_mask(
    const unsigned* __restrict__ fired, float* __restrict__ out) {
    int b = blockIdx.x;
    int n = threadIdx.x;                  // 512
    unsigned f = fired[(size_t)b * NN + n];
    __shared__ int wsum[8];
    unsigned long long m = __ballot(f != 0u);
    int lane = n & 63;
    int w = n >> 6;
    if (lane == 0) wsum[w] = __popcll(m);
    __syncthreads();
    int cnt = 0;
    #pragma unroll
    for (int i = 0; i < 8; ++i) cnt += wsum[i];
    float val = (cnt == 0) ? 1.0f : ((cnt == 1) ? (f ? 1.0f : 0.0f) : 0.0f);
    out[(size_t)b * NN + n] = val;
}

extern "C" void kernel_launch(void* const* d_in, const int* in_sizes, int n_in,
                              void* d_out, int out_size, void* d_ws, size_t ws_size,
                              hipStream_t stream) {
    const float* x = (const float*)d_in[0];
    float* out = (float*)d_out;

    // ws layout
    float* s1p = (float*)d_ws;                       // B*TCH*N
    float* s2p = s1p + (size_t)BB * TCH * NN;        // B*TCH*N
    float* s1  = s2p + (size_t)BB * TCH * NN;        // B*N
    float* dv  = s1  + (size_t)BB * NN;              // B*N
    unsigned* fired = (unsigned*)(dv + (size_t)BB * NN); // B*N

    hipMemsetAsync(fired, 0, (size_t)BB * NN * sizeof(unsigned), stream);

    colsum_partial<<<dim3(BB, TCH), 512, 0, stream>>>(x, s1p, s2p);
    colsum_reduce<<<BB, 512, 0, stream>>>(s1p, s2p, s1, dv);
    corr_mfma<<<dim3(640), 512, 0, stream>>>(x, s1, dv, fired);
    finalize_mask<<<BB, 512, 0, stream>>>(fired, out);
}